// Round 2
// baseline (1943.696 us; speedup 1.0000x reference)
//
#include <hip/hip_runtime.h>
#include <math.h>

#define B_ 8
#define T_ 1000
#define F_ 96
#define C_ 16
#define D_ 64
#define EPS_ 1e-5f

__device__ __forceinline__ float gelu_erf(float v){
    return 0.5f*v*(1.0f+erff(v*0.70710678118654752440f));
}
__device__ __forceinline__ float sigmoidf(float v){
    return 1.0f/(1.0f+expf(-v));
}
// wave-synchronous LDS fence: per-wave LDS ops complete in order; the fence
// (s_waitcnt lgkmcnt(0)) + wave_barrier stops compiler reordering.
__device__ __forceinline__ void wsync(){
    __builtin_amdgcn_wave_barrier();
    __threadfence_block();
    __builtin_amdgcn_wave_barrier();
}

// ---------------- Kernel A: conv_in -> x [B,T,F,C] ----------------
__global__ __launch_bounds__(128) void k_conv_in(
    const float* __restrict__ in, const float* __restrict__ g, const float* __restrict__ bb,
    const float* __restrict__ w_in, const float* __restrict__ b_in,
    float* __restrict__ x)
{
    int bt = blockIdx.x; int b = bt / T_; int t = bt % T_;
    int tid = threadIdx.x;
    __shared__ float r0[128], r1[128], r2[128], r3[128];
    float i0=0.f, i1=0.f;
    size_t base0 = ((size_t)(b*2+0)*T_ + t)*F_;
    size_t base1 = ((size_t)(b*2+1)*T_ + t)*F_;
    if (tid < F_){ i0 = in[base0+tid]; i1 = in[base1+tid]; }
    r0[tid]=i0; r1[tid]=i0*i0; r2[tid]=i1; r3[tid]=i1*i1;
    __syncthreads();
    for (int s=64; s>0; s>>=1){
        if (tid < s){ r0[tid]+=r0[tid+s]; r1[tid]+=r1[tid+s]; r2[tid]+=r2[tid+s]; r3[tid]+=r3[tid+s]; }
        __syncthreads();
    }
    float m0 = r0[0]*(1.f/F_), m1 = r2[0]*(1.f/F_);
    float ri0 = rsqrtf(r1[0]*(1.f/F_) - m0*m0 + EPS_);
    float ri1 = rsqrtf(r3[0]*(1.f/F_) - m1*m1 + EPS_);
    if (tid < F_){
        float gg = g[tid], b0 = bb[tid];
        float y0 = (i0-m0)*ri0*gg + b0;
        float y1 = (i1-m1)*ri1*gg + b0;
        float xv[16];
        #pragma unroll
        for (int c=0;c<C_;++c){
            xv[c] = gelu_erf(w_in[c*2+0]*y0 + w_in[c*2+1]*y1 + b_in[c]);
        }
        float4* xp = (float4*)(x + (((size_t)b*T_+t)*F_ + tid)*C_);
        xp[0] = make_float4(xv[0],xv[1],xv[2],xv[3]);
        xp[1] = make_float4(xv[4],xv[5],xv[6],xv[7]);
        xp[2] = make_float4(xv[8],xv[9],xv[10],xv[11]);
        xp[3] = make_float4(xv[12],xv[13],xv[14],xv[15]);
    }
}

// ---------------- Kernel B: ConvGRU, one wave per (b,f) chain ----------------
// 768 blocks x 64 threads. lane = c + 16*qg; qg-group holds k in [4qg,4qg+4).
__global__ __launch_bounds__(64) void k_gru(
    const float* __restrict__ x, const float* __restrict__ wx, const float* __restrict__ wh,
    float* __restrict__ hs, float* __restrict__ d_out)
{
    int blk = blockIdx.x;
    int b = blk / 96, f = blk % 96;
    int lane = threadIdx.x;
    int c = lane & 15, qg = lane >> 4;

    const float4 wxz = *(const float4*)(wx + ( 0+c)*16 + 4*qg);
    const float4 wxr = *(const float4*)(wx + (16+c)*16 + 4*qg);
    const float4 wxn = *(const float4*)(wx + (32+c)*16 + 4*qg);
    const float4 whz = *(const float4*)(wh + ( 0+c)*16 + 4*qg);
    const float4 whr = *(const float4*)(wh + (16+c)*16 + 4*qg);
    const float4 whn = *(const float4*)(wh + (32+c)*16 + 4*qg);

    size_t base = ((size_t)b*T_*F_ + f)*C_;         // element index of [b][0][f][0]
    const float4* xp = (const float4*)(x + base + 4*qg);  // stride per t: 384 float4

    float4 h4 = make_float4(0.f,0.f,0.f,0.f);
    float hc = 0.f;
    float4 xv = xp[0];
    float hn = 0.f;
    for (int t=0;t<T_;++t){
        float4 xn = xv;
        if (t+1 < T_) xn = xp[(size_t)(t+1)*384];
        float sz  = wxz.x*xv.x + wxz.y*xv.y + wxz.z*xv.z + wxz.w*xv.w
                  + whz.x*h4.x + whz.y*h4.y + whz.z*h4.z + whz.w*h4.w;
        float sr  = wxr.x*xv.x + wxr.y*xv.y + wxr.z*xv.z + wxr.w*xv.w
                  + whr.x*h4.x + whr.y*h4.y + whr.z*h4.z + whr.w*h4.w;
        float snx = wxn.x*xv.x + wxn.y*xv.y + wxn.z*xv.z + wxn.w*xv.w;
        float snh = whn.x*h4.x + whn.y*h4.y + whn.z*h4.z + whn.w*h4.w;
        sz  += __shfl_xor(sz ,16); sz  += __shfl_xor(sz ,32);
        sr  += __shfl_xor(sr ,16); sr  += __shfl_xor(sr ,32);
        snx += __shfl_xor(snx,16); snx += __shfl_xor(snx,32);
        snh += __shfl_xor(snh,16); snh += __shfl_xor(snh,32);
        float z = sigmoidf(sz);
        float r = sigmoidf(sr);
        float n = tanhf(snx + r*snh);
        hn = (1.f - z)*n + z*hc;
        hc = hn;
        h4.x = __shfl(hn, 4*qg+0);
        h4.y = __shfl(hn, 4*qg+1);
        h4.z = __shfl(hn, 4*qg+2);
        h4.w = __shfl(hn, 4*qg+3);
        if (lane < 16) hs[base + (size_t)t*(F_*C_) + c] = hn;
        xv = xn;
    }
    if (lane < 16)
        d_out[(size_t)B_*2*T_*F_ + ((size_t)b*C_ + c)*F_ + f] = hc;
}

// ---------------- Kernel C: fused attention + MLP + conv_out ----------------
// LDS layout (floats):
#define OX2   0            // x2/y/x3 [16][97]            1552
#define OKL   1552         // klb [24][65]  (base%32==16) 1560 ; MLP reuse: ynorm[16*97]
#define OVL   3112         // vlb [24][65]                1560 ; MLP reuse: y1 at OKL+1552
#define OWQ   4672         // wqT [16][64] c*64+d         1024
#define OWK   5696         // wkT                         1024
#define OWV   6720         // wvT                         1024
#define OWO   7744         // woT [64][17] d*17+c         1088
#define OYM   8832         // ymean [16][25] c*25+s        400
#define OMEA  9232         // 16
#define ORSTD 9248         // 16 (+16 pad)
#define OWS   9280         // per-wave scratch, stride 672 (base%32==0):
                           //   k: +0 [4][65]  q: +260 [4][65]  a: +520 [4][32]
#define WSSTR 672
#define TOTF  (OWS + 4*WSSTR)   // 11968 floats = 47872 B

__device__ __forceinline__ void ln_stats(const float* buf, float* mea, float* rstd, int tid){
    int row = tid >> 4, j = tid & 15;
    float s=0.f, q=0.f;
    #pragma unroll
    for (int i=0;i<6;++i){
        float v = buf[row*97 + j + 16*i];
        s += v; q += v*v;
    }
    #pragma unroll
    for (int off=8; off; off>>=1){
        s += __shfl_down(s, off, 16);
        q += __shfl_down(q, off, 16);
    }
    if (j==0){
        float m = s*(1.f/96.f);
        mea[row] = m;
        rstd[row] = rsqrtf(q*(1.f/96.f) - m*m + EPS_);
    }
}

__global__ __launch_bounds__(256) void k_tail(
    const float* __restrict__ x, const float* __restrict__ hs, const float* __restrict__ input,
    const float* __restrict__ ln_att_g, const float* __restrict__ ln_att_b,
    const float* __restrict__ wq, const float* __restrict__ bq,
    const float* __restrict__ wk, const float* __restrict__ bk,
    const float* __restrict__ wv, const float* __restrict__ bv,
    const float* __restrict__ wo, const float* __restrict__ bo,
    const float* __restrict__ ln_m_g, const float* __restrict__ ln_m_b,
    const float* __restrict__ wm1, const float* __restrict__ bm1,
    const float* __restrict__ wm2, const float* __restrict__ bm2,
    const float* __restrict__ ln_o_g, const float* __restrict__ ln_o_b,
    const float* __restrict__ w_out, const float* __restrict__ b_out,
    float* __restrict__ out)
{
    int bt = blockIdx.x; int b = bt / T_; int t = bt % T_;
    int tid = threadIdx.x;
    int w = tid >> 6, lane = tid & 63;
    __shared__ float S[TOTF];

    size_t xbase = ((size_t)b*T_ + t)*(size_t)(F_*C_);

    // P0: x2 = x + hs  (global coalesced, LDS [c][f]); stage weights
    for (int idx=tid; idx<1536; idx+=256){
        int c = idx & 15, f = idx >> 4;
        S[OX2 + c*97 + f] = x[xbase+idx] + hs[xbase+idx];
    }
    for (int idx=tid; idx<1024; idx+=256){
        int c = idx & 15, d = idx >> 4;             // idx = d*16+c
        S[OWQ + c*64 + d] = wq[idx];
        S[OWK + c*64 + d] = wk[idx];
        S[OWV + c*64 + d] = wv[idx];
    }
    for (int idx=tid; idx<1024; idx+=256){
        int d = idx & 63, c = idx >> 6;             // idx = c*64+d
        S[OWO + d*17 + c] = wo[idx];
    }
    __syncthreads();

    // P1/P2: attention LN
    ln_stats(S+OX2, S+OMEA, S+ORSTD, tid);
    __syncthreads();
    for (int idx=tid; idx<1536; idx+=256){
        int f = idx % 96, c = idx / 96;
        float v = S[OX2 + c*97 + f];
        S[OX2 + c*97 + f] = (v - S[OMEA+c])*S[ORSTD+c]*ln_att_g[f] + ln_att_b[f];
    }
    __syncthreads();

    // P3: segment means of y
    for (int idx=tid; idx<384; idx+=256){
        int sm = idx % 24, c = idx / 24;
        S[OYM + c*25 + sm] = 0.25f*(S[OX2+c*97+4*sm] + S[OX2+c*97+4*sm+1]
                                  + S[OX2+c*97+4*sm+2] + S[OX2+c*97+4*sm+3]);
    }
    __syncthreads();

    // P4: k_long / v_long
    for (int idx=tid; idx<3072; idx+=256){
        int sm = idx % 24, d = (idx/24) & 63;
        if (idx < 1536){
            float acc = bk[d];
            #pragma unroll
            for (int c=0;c<16;++c) acc += S[OWK+c*64+d]*S[OYM+c*25+sm];
            S[OKL + sm*65 + d] = acc;
        } else {
            float acc = bv[d];
            #pragma unroll
            for (int c=0;c<16;++c) acc += S[OWV+c*64+d]*S[OYM+c*25+sm];
            S[OVL + sm*65 + d] = acc;
        }
    }
    __syncthreads();

    // P5: attention — each wave owns 6 segments, wave-synchronous (no block barriers)
    float* wsK = S + OWS + w*WSSTR;
    float* wsQ = wsK + 260;
    float* wsA = wsK + 520;
    for (int si=0; si<6; ++si){
        int s = 4*si + w;
        int d = lane;
        float vr[4];
        // q,k into scratch; v into registers (lane=d holds v[r][d])
        #pragma unroll
        for (int r=0;r<4;++r){
            int fc = 4*s + r;
            float aq = bq[d], ak = bk[d], av = bv[d];
            #pragma unroll
            for (int c=0;c<16;++c){
                float yv = S[OX2 + c*97 + fc];      // broadcast
                aq += S[OWQ+c*64+d]*yv;
                ak += S[OWK+c*64+d]*yv;
                av += S[OWV+c*64+d]*yv;
            }
            wsQ[r*65+d] = aq;
            wsK[r*65+d] = ak;
            vr[r] = av;
        }
        wsync();
        // scores: lane = (r = lane>>4, jj = lane&15); keys jj and jj+16 (28 valid)
        {
            int r = lane >> 4, jj = lane & 15;
            const float* qrow = wsQ + r*65;
            const float* k1 = (jj < 4) ? (wsK + jj*65) : (S + OKL + (jj-4)*65);
            const float* k2 = S + OKL + (jj+12)*65;
            float a1 = 0.f, a2 = 0.f;
            #pragma unroll
            for (int dd=0; dd<64; ++dd){
                float qv = qrow[dd];
                a1 += qv*k1[dd];
                a2 += qv*k2[dd];
            }
            float s1 = a1*0.125f;
            float s2 = (jj < 12) ? a2*0.125f : -INFINITY;
            float mx = fmaxf(s1, s2);
            #pragma unroll
            for (int off=8; off; off>>=1) mx = fmaxf(mx, __shfl_xor(mx, off, 16));
            float p1 = expf(s1 - mx);
            float p2 = (jj < 12) ? expf(s2 - mx) : 0.f;
            float sm = p1 + p2;
            #pragma unroll
            for (int off=8; off; off>>=1) sm += __shfl_xor(sm, off, 16);
            float inv = 1.f/sm;
            wsA[r*32 + jj] = p1*inv;
            if (jj < 12) wsA[r*32 + 16 + jj] = p2*inv;
        }
        wsync();
        // o: lane=d; o rows overwrite wsK
        #pragma unroll
        for (int r=0;r<4;++r){
            float o = wsA[r*32+0]*vr[0] + wsA[r*32+1]*vr[1]
                    + wsA[r*32+2]*vr[2] + wsA[r*32+3]*vr[3];
            #pragma unroll
            for (int m=0;m<24;++m) o += wsA[r*32+4+m]*S[OVL + m*65 + d];
            wsK[r*65+d] = o;
        }
        wsync();
        // out-proj + residual, write x3 in place (column owned by this wave)
        {
            int r = lane >> 4, cc = lane & 15;
            int fc = 4*s + r;
            float acc = bo[cc];
            #pragma unroll
            for (int dd=0; dd<64; ++dd) acc += S[OWO + dd*17 + cc]*wsK[r*65+dd];
            float resid = x[xbase + fc*16 + cc] + hs[xbase + fc*16 + cc];
            S[OX2 + cc*97 + fc] = resid + acc;
        }
        wsync();
    }
    __syncthreads();

    // P6: MLP (ynorm at OKL, y1 at OKL+1552 — klb/vlb region reused)
    ln_stats(S+OX2, S+OMEA, S+ORSTD, tid);
    __syncthreads();
    for (int idx=tid; idx<1536; idx+=256){
        int f = idx % 96, c = idx / 96;
        S[OKL + c*97 + f] = (S[OX2+c*97+f]-S[OMEA+c])*S[ORSTD+c]*ln_m_g[f] + ln_m_b[f];
    }
    __syncthreads();
    for (int idx=tid; idx<1536; idx+=256){
        int f = idx % 96, c2 = idx / 96;
        float acc = bm1[c2];
        #pragma unroll
        for (int c=0;c<16;++c) acc += wm1[c2*16+c]*S[OKL + c*97 + f];
        S[OKL + 1552 + c2*97 + f] = gelu_erf(acc);
    }
    __syncthreads();
    for (int idx=tid; idx<1536; idx+=256){
        int f = idx % 96, c = idx / 96;
        float acc = bm2[c];
        #pragma unroll
        for (int k=0;k<16;++k) acc += wm2[c*16+k]*S[OKL + 1552 + k*97 + f];
        S[OX2 + c*97 + f] += acc;
    }
    __syncthreads();

    // P7: conv_out + outer residual
    ln_stats(S+OX2, S+OMEA, S+ORSTD, tid);
    __syncthreads();
    if (tid < 192){
        int ch = tid / 96, f = tid % 96;
        float gg = ln_o_g[f], b2 = ln_o_b[f];
        float acc = b_out[ch];
        #pragma unroll
        for (int c=0;c<16;++c)
            acc += w_out[ch*16+c]*((S[OX2+c*97+f]-S[OMEA+c])*S[ORSTD+c]*gg + b2);
        size_t oidx = ((size_t)(b*2+ch)*T_ + t)*F_ + f;
        out[oidx] = input[oidx] + tanhf(acc);
    }
}

extern "C" void kernel_launch(void* const* d_in, const int* in_sizes, int n_in,
                              void* d_out, int out_size, void* d_ws, size_t ws_size,
                              hipStream_t stream)
{
    const float* input   = (const float*)d_in[0];
    const float* ln_in_g = (const float*)d_in[1];
    const float* ln_in_b = (const float*)d_in[2];
    const float* w_in    = (const float*)d_in[3];
    const float* b_in    = (const float*)d_in[4];
    const float* gru_wx  = (const float*)d_in[5];
    const float* gru_wh  = (const float*)d_in[6];
    const float* ln_att_g= (const float*)d_in[7];
    const float* ln_att_b= (const float*)d_in[8];
    const float* wq = (const float*)d_in[9];
    const float* bq = (const float*)d_in[10];
    const float* wk = (const float*)d_in[11];
    const float* bk = (const float*)d_in[12];
    const float* wv = (const float*)d_in[13];
    const float* bv = (const float*)d_in[14];
    const float* wo = (const float*)d_in[15];
    const float* bo = (const float*)d_in[16];
    const float* ln_m_g = (const float*)d_in[17];
    const float* ln_m_b = (const float*)d_in[18];
    const float* w_m1 = (const float*)d_in[19];
    const float* b_m1 = (const float*)d_in[20];
    const float* w_m2 = (const float*)d_in[21];
    const float* b_m2 = (const float*)d_in[22];
    const float* ln_out_g = (const float*)d_in[23];
    const float* ln_out_b = (const float*)d_in[24];
    const float* w_out = (const float*)d_in[25];
    const float* b_out = (const float*)d_in[26];
    float* out = (float*)d_out;

    float* x  = (float*)d_ws;                       // [B,T,F,C]
    float* hs = x + (size_t)B_*T_*F_*C_;            // [B,T,F,C]

    k_conv_in<<<B_*T_, 128, 0, stream>>>(input, ln_in_g, ln_in_b, w_in, b_in, x);
    k_gru<<<768, 64, 0, stream>>>(x, gru_wx, gru_wh, hs, out);
    k_tail<<<B_*T_, 256, 0, stream>>>(x, hs, input, ln_att_g, ln_att_b,
        wq, bq, wk, bk, wv, bv, wo, bo, ln_m_g, ln_m_b, w_m1, b_m1, w_m2, b_m2,
        ln_out_g, ln_out_b, w_out, b_out, out);
}

// Round 3
// 1078.933 us; speedup vs baseline: 1.8015x; 1.8015x over previous
//
#include <hip/hip_runtime.h>
#include <math.h>

#define B_ 8
#define T_ 1000
#define F_ 96
#define C_ 16
#define D_ 64
#define EPS_ 1e-5f

__device__ __forceinline__ float gelu_erf(float v){
    return 0.5f*v*(1.0f+erff(v*0.70710678118654752440f));
}
__device__ __forceinline__ float sigmoidf(float v){
    return 1.0f/(1.0f+expf(-v));
}
__device__ __forceinline__ float dot4(float4 a, float4 b){
    return a.x*b.x + a.y*b.y + a.z*b.z + a.w*b.w;
}
// wave-synchronous LDS fence (validated round 2: per-wave LDS ops are in-order)
__device__ __forceinline__ void wsync(){
    __builtin_amdgcn_wave_barrier();
    __threadfence_block();
    __builtin_amdgcn_wave_barrier();
}

// ---------------- Kernel A: conv_in -> x [B,T,F,C] ----------------
__global__ __launch_bounds__(128) void k_conv_in(
    const float* __restrict__ in, const float* __restrict__ g, const float* __restrict__ bb,
    const float* __restrict__ w_in, const float* __restrict__ b_in,
    float* __restrict__ x)
{
    int bt = blockIdx.x; int b = bt / T_; int t = bt % T_;
    int tid = threadIdx.x;
    __shared__ float r0[128], r1[128], r2[128], r3[128];
    float i0=0.f, i1=0.f;
    size_t base0 = ((size_t)(b*2+0)*T_ + t)*F_;
    size_t base1 = ((size_t)(b*2+1)*T_ + t)*F_;
    if (tid < F_){ i0 = in[base0+tid]; i1 = in[base1+tid]; }
    r0[tid]=i0; r1[tid]=i0*i0; r2[tid]=i1; r3[tid]=i1*i1;
    __syncthreads();
    for (int s=64; s>0; s>>=1){
        if (tid < s){ r0[tid]+=r0[tid+s]; r1[tid]+=r1[tid+s]; r2[tid]+=r2[tid+s]; r3[tid]+=r3[tid+s]; }
        __syncthreads();
    }
    float m0 = r0[0]*(1.f/F_), m1 = r2[0]*(1.f/F_);
    float ri0 = rsqrtf(r1[0]*(1.f/F_) - m0*m0 + EPS_);
    float ri1 = rsqrtf(r3[0]*(1.f/F_) - m1*m1 + EPS_);
    if (tid < F_){
        float gg = g[tid], b0 = bb[tid];
        float y0 = (i0-m0)*ri0*gg + b0;
        float y1 = (i1-m1)*ri1*gg + b0;
        float xv[16];
        #pragma unroll
        for (int c=0;c<C_;++c){
            xv[c] = gelu_erf(w_in[c*2+0]*y0 + w_in[c*2+1]*y1 + b_in[c]);
        }
        float4* xp = (float4*)(x + (((size_t)b*T_+t)*F_ + tid)*C_);
        xp[0] = make_float4(xv[0],xv[1],xv[2],xv[3]);
        xp[1] = make_float4(xv[4],xv[5],xv[6],xv[7]);
        xp[2] = make_float4(xv[8],xv[9],xv[10],xv[11]);
        xp[3] = make_float4(xv[12],xv[13],xv[14],xv[15]);
    }
}

// ---------------- Kernel B: ConvGRU, one wave per (b,f) chain, 4-deep prefetch ----------------
__global__ __launch_bounds__(64) void k_gru(
    const float* __restrict__ x, const float* __restrict__ wx, const float* __restrict__ wh,
    float* __restrict__ hs, float* __restrict__ d_out)
{
    int blk = blockIdx.x;
    int b = blk / 96, f = blk % 96;
    int lane = threadIdx.x;
    int c = lane & 15, qg = lane >> 4;

    const float4 wxz = *(const float4*)(wx + ( 0+c)*16 + 4*qg);
    const float4 wxr = *(const float4*)(wx + (16+c)*16 + 4*qg);
    const float4 wxn = *(const float4*)(wx + (32+c)*16 + 4*qg);
    const float4 whz = *(const float4*)(wh + ( 0+c)*16 + 4*qg);
    const float4 whr = *(const float4*)(wh + (16+c)*16 + 4*qg);
    const float4 whn = *(const float4*)(wh + (32+c)*16 + 4*qg);

    size_t base = ((size_t)b*T_*F_ + f)*C_;
    const float4* xp = (const float4*)(x + base + 4*qg);   // stride per t: 384 float4

    float4 h4 = make_float4(0.f,0.f,0.f,0.f);
    float hc = 0.f;
    float4 xq0 = xp[0], xq1 = xp[384], xq2 = xp[768], xq3 = xp[1152];

#define GRU_STEP(XV, TT) { \
        float sz  = wxz.x*XV.x + wxz.y*XV.y + wxz.z*XV.z + wxz.w*XV.w \
                  + whz.x*h4.x + whz.y*h4.y + whz.z*h4.z + whz.w*h4.w; \
        float sr  = wxr.x*XV.x + wxr.y*XV.y + wxr.z*XV.z + wxr.w*XV.w \
                  + whr.x*h4.x + whr.y*h4.y + whr.z*h4.z + whr.w*h4.w; \
        float snx = wxn.x*XV.x + wxn.y*XV.y + wxn.z*XV.z + wxn.w*XV.w; \
        float snh = whn.x*h4.x + whn.y*h4.y + whn.z*h4.z + whn.w*h4.w; \
        sz  += __shfl_xor(sz ,16); sz  += __shfl_xor(sz ,32); \
        sr  += __shfl_xor(sr ,16); sr  += __shfl_xor(sr ,32); \
        snx += __shfl_xor(snx,16); snx += __shfl_xor(snx,32); \
        snh += __shfl_xor(snh,16); snh += __shfl_xor(snh,32); \
        float z = sigmoidf(sz); \
        float r = sigmoidf(sr); \
        float n = tanhf(snx + r*snh); \
        float hn = (1.f - z)*n + z*hc; \
        hc = hn; \
        h4.x = __shfl(hn, 4*qg+0); \
        h4.y = __shfl(hn, 4*qg+1); \
        h4.z = __shfl(hn, 4*qg+2); \
        h4.w = __shfl(hn, 4*qg+3); \
        if (lane < 16) hs[base + (size_t)(TT)*(F_*C_) + c] = hn; \
    }

    for (int t=0; t<T_; t+=4){
        float4 n0, n1, n2, n3;
        bool pf = (t+4 < T_);
        if (pf){
            n0 = xp[(size_t)(t+4)*384];
            n1 = xp[(size_t)(t+5)*384];
            n2 = xp[(size_t)(t+6)*384];
            n3 = xp[(size_t)(t+7)*384];
        }
        GRU_STEP(xq0, t+0);
        GRU_STEP(xq1, t+1);
        GRU_STEP(xq2, t+2);
        GRU_STEP(xq3, t+3);
        if (pf){ xq0=n0; xq1=n1; xq2=n2; xq3=n3; }
    }
#undef GRU_STEP
    if (lane < 16)
        d_out[(size_t)B_*2*T_*F_ + ((size_t)b*C_ + c)*F_ + f] = hc;
}

// ---------------- Kernel C: fused attention + MLP + conv_out ----------------
// LDS map (floats). All float4-read bases 16B aligned; strides chosen for <=2-way banks.
#define OX2   0        // x2/y/x3 [96][16]  f*16+c            1536
#define OYM   1536     // ymean [24][16]  m*16+c               384
#define OKL   1920     // k_long [24][68]                     1632
#define OVL   3552     // v_long [24][68]                     1632
#define OWQ   5184     // wq as float4 tiles: f4idx=c4*64+d   1024
#define OWK   6208
#define OWV   7232
#define OWO   8256     // wo as float4 tiles: f4idx=dd4*16+cc 1024
#define OWM1  9280     // [16][16]                             256
#define OWM2  9536     //                                      256
#define OMEA  9792     // 16
#define ORST  9808     // 16
#define OSC   9824     // LN partial scratch 512
#define OWS   10336    // per-wave scratch x4, stride 672: K[4*68] Q[4*68] A[112+pad]
#define WSSTR 672
#define TOTF  (OWS + 4*WSSTR)   // 13024 floats = 52096 B

__device__ __forceinline__ void ln_stats16(float* S, int tid){
    int c = tid & 15, g = tid >> 4;
    float s=0.f, q=0.f;
    #pragma unroll
    for (int i=0;i<6;++i){
        float v = S[OX2 + (g*6+i)*16 + c];
        s += v; q += v*v;
    }
    S[OSC + g*16 + c] = s;
    S[OSC + 256 + g*16 + c] = q;
    __syncthreads();
    if (tid < 16){
        float Sm=0.f, Q=0.f;
        #pragma unroll
        for (int g2=0; g2<16; ++g2){
            Sm += S[OSC + g2*16 + tid];
            Q  += S[OSC + 256 + g2*16 + tid];
        }
        float m = Sm*(1.f/96.f);
        S[OMEA+tid] = m;
        S[ORST+tid] = rsqrtf(Q*(1.f/96.f) - m*m + EPS_);
    }
    __syncthreads();
}

__global__ __launch_bounds__(256) void k_tail(
    const float* __restrict__ x, const float* __restrict__ hs, const float* __restrict__ input,
    const float* __restrict__ ln_att_g, const float* __restrict__ ln_att_b,
    const float* __restrict__ wq, const float* __restrict__ bq,
    const float* __restrict__ wk, const float* __restrict__ bk,
    const float* __restrict__ wv, const float* __restrict__ bv,
    const float* __restrict__ wo, const float* __restrict__ bo,
    const float* __restrict__ ln_m_g, const float* __restrict__ ln_m_b,
    const float* __restrict__ wm1, const float* __restrict__ bm1,
    const float* __restrict__ wm2, const float* __restrict__ bm2,
    const float* __restrict__ ln_o_g, const float* __restrict__ ln_o_b,
    const float* __restrict__ w_out, const float* __restrict__ b_out,
    float* __restrict__ out)
{
    int bt = blockIdx.x; int b = bt / T_; int t = bt % T_;
    int tid = threadIdx.x;
    int w = tid >> 6, lane = tid & 63;
    __shared__ float S[TOTF];
    float4* X2f4 = (float4*)(S + OX2);
    float4* YM4  = (float4*)(S + OYM);
    const float4* WQ4 = (const float4*)(S + OWQ);
    const float4* WK4 = (const float4*)(S + OWK);
    const float4* WV4 = (const float4*)(S + OWV);
    const float4* WO4 = (const float4*)(S + OWO);

    size_t xbase = ((size_t)b*T_ + t)*(size_t)(F_*C_);

    // lane-resident biases (lane = d for qkv phases; lane&15 = c for out-proj)
    float bq_r = bq[lane], bk_r = bk[lane], bv_r = bv[lane];
    float bo_r = bo[lane & 15];

    // P0: x2 = x + hs (float4 coalesced); stage weights as float4 tiles
    {
        const float4* xg = (const float4*)(x + xbase);
        const float4* hg = (const float4*)(hs + xbase);
        for (int i4 = tid; i4 < 384; i4 += 256){
            float4 a = xg[i4], h = hg[i4];
            X2f4[i4] = make_float4(a.x+h.x, a.y+h.y, a.z+h.z, a.w+h.w);
        }
        // wq/wk/wv global [64][16]: tid -> d=tid>>2, c4=tid&3 ; store f4idx c4*64+d
        {
            int d = tid >> 2, c4 = tid & 3;
            ((float4*)(S+OWQ))[c4*64 + d] = ((const float4*)wq)[tid];
            ((float4*)(S+OWK))[c4*64 + d] = ((const float4*)wk)[tid];
            ((float4*)(S+OWV))[c4*64 + d] = ((const float4*)wv)[tid];
        }
        // wo global [16][64]: tid -> c=tid>>4, dd4=tid&15 ; store f4idx dd4*16+c
        {
            int c2 = tid >> 4, dd4 = tid & 15;
            ((float4*)(S+OWO))[dd4*16 + c2] = ((const float4*)wo)[tid];
        }
        S[OWM1 + tid] = wm1[tid];
        S[OWM2 + tid] = wm2[tid];
    }
    __syncthreads();

    // P1/P2: attention LN
    ln_stats16(S, tid);
    for (int i4 = tid; i4 < 384; i4 += 256){
        int f = i4 >> 2, c4 = i4 & 3;
        float4 v = X2f4[i4];
        float4 m4 = *(float4*)(S + OMEA + 4*c4);
        float4 r4 = *(float4*)(S + ORST + 4*c4);
        float gg = ln_att_g[f], b2 = ln_att_b[f];
        v.x = (v.x - m4.x)*r4.x*gg + b2;
        v.y = (v.y - m4.y)*r4.y*gg + b2;
        v.z = (v.z - m4.z)*r4.z*gg + b2;
        v.w = (v.w - m4.w)*r4.w*gg + b2;
        X2f4[i4] = v;
    }
    __syncthreads();

    // P3: segment means
    for (int i4 = tid; i4 < 96; i4 += 256){
        int m = i4 >> 2, c4 = i4 & 3;
        float4 a0 = X2f4[(4*m+0)*4 + c4];
        float4 a1 = X2f4[(4*m+1)*4 + c4];
        float4 a2 = X2f4[(4*m+2)*4 + c4];
        float4 a3 = X2f4[(4*m+3)*4 + c4];
        YM4[m*4 + c4] = make_float4(0.25f*(a0.x+a1.x+a2.x+a3.x), 0.25f*(a0.y+a1.y+a2.y+a3.y),
                                    0.25f*(a0.z+a1.z+a2.z+a3.z), 0.25f*(a0.w+a1.w+a2.w+a3.w));
    }
    __syncthreads();

    // P4: k_long/v_long — wave w computes m = 6w..6w+5, lane = d
    {
        int m0 = 6*w;
        float ak[6], av[6];
        #pragma unroll
        for (int j=0;j<6;++j){ ak[j] = bk_r; av[j] = bv_r; }
        #pragma unroll
        for (int c4=0;c4<4;++c4){
            float4 k4 = WK4[c4*64 + lane];
            float4 v4 = WV4[c4*64 + lane];
            #pragma unroll
            for (int j=0;j<6;++j){
                float4 y4 = YM4[(m0+j)*4 + c4];     // broadcast
                ak[j] += dot4(k4, y4);
                av[j] += dot4(v4, y4);
            }
        }
        #pragma unroll
        for (int j=0;j<6;++j){
            S[OKL + (m0+j)*68 + lane] = ak[j];
            S[OVL + (m0+j)*68 + lane] = av[j];
        }
    }
    __syncthreads();

    // P5: attention — wave w owns segments 6w..6w+5; wave-synchronous
    float* wsK = S + OWS + w*WSSTR;
    float* wsQ = wsK + 272;
    float* wsA = wsK + 544;                 // transposed: a[key j][r]
    float4* wsA4 = (float4*)wsA;
    for (int si=0; si<6; ++si){
        int s = 6*w + si;
        // qkv for the 4 rows of this segment (lane = d)
        float aq[4], ak2[4], av2[4];
        #pragma unroll
        for (int r=0;r<4;++r){ aq[r]=bq_r; ak2[r]=bk_r; av2[r]=bv_r; }
        #pragma unroll
        for (int c4=0;c4<4;++c4){
            float4 q4 = WQ4[c4*64 + lane];
            float4 k4 = WK4[c4*64 + lane];
            float4 v4 = WV4[c4*64 + lane];
            #pragma unroll
            for (int r=0;r<4;++r){
                float4 y4 = X2f4[(4*s+r)*4 + c4];    // broadcast
                aq[r] += dot4(q4, y4);
                ak2[r] += dot4(k4, y4);
                av2[r] += dot4(v4, y4);
            }
        }
        #pragma unroll
        for (int r=0;r<4;++r){
            wsQ[r*68 + lane] = aq[r];
            wsK[r*68 + lane] = ak2[r];
        }
        wsync();
        // scores + softmax: lane = (r2 = lane>>4, jj = lane&15); keys jj (4 loc + 12 long) and jj+16
        {
            int r2 = lane >> 4, jj = lane & 15;
            const float* qrow = wsQ + r2*68;
            const float* k1 = (jj < 4) ? (wsK + jj*68) : (S + OKL + (jj-4)*68);
            const float* k2p = S + OKL + (jj+12)*68;   // valid only jj<12 (guarded below)
            float a1 = 0.f, a2 = 0.f;
            #pragma unroll
            for (int dd4=0; dd4<16; ++dd4){
                float4 q4  = *(const float4*)(qrow + 4*dd4);
                float4 k14 = *(const float4*)(k1   + 4*dd4);
                float4 k24 = *(const float4*)(k2p  + 4*dd4);
                a1 += dot4(q4, k14);
                a2 += dot4(q4, k24);
            }
            float s1 = a1*0.125f;
            float s2 = (jj < 12) ? a2*0.125f : -INFINITY;
            float mx = fmaxf(s1, s2);
            #pragma unroll
            for (int off=8; off; off>>=1) mx = fmaxf(mx, __shfl_xor(mx, off, 16));
            float p1 = expf(s1 - mx);
            float p2 = (jj < 12) ? expf(s2 - mx) : 0.f;
            float sm = p1 + p2;
            #pragma unroll
            for (int off=8; off; off>>=1) sm += __shfl_xor(sm, off, 16);
            float inv = 1.f/sm;
            wsA[jj*4 + r2] = p1*inv;
            if (jj < 12) wsA[(16+jj)*4 + r2] = p2*inv;
        }
        wsync();
        // o = a_loc·v_loc + a_long·v_long  (lane = d); overwrite wsK rows with o
        {
            float o0, o1, o2, o3;
            float4 aj = wsA4[0];
            o0 = aj.x*av2[0]; o1 = aj.y*av2[0]; o2 = aj.z*av2[0]; o3 = aj.w*av2[0];
            #pragma unroll
            for (int j=1;j<4;++j){
                aj = wsA4[j];
                o0 += aj.x*av2[j]; o1 += aj.y*av2[j]; o2 += aj.z*av2[j]; o3 += aj.w*av2[j];
            }
            #pragma unroll
            for (int m=0;m<24;++m){
                float vm = S[OVL + m*68 + lane];
                float4 am = wsA4[4+m];              // broadcast
                o0 += am.x*vm; o1 += am.y*vm; o2 += am.z*vm; o3 += am.w*vm;
            }
            wsync();                                 // everyone done reading wsK (scores)
            wsK[0*68 + lane] = o0;
            wsK[1*68 + lane] = o1;
            wsK[2*68 + lane] = o2;
            wsK[3*68 + lane] = o3;
        }
        wsync();
        // out-proj + residual -> x3 written into X2 (rows owned by this wave)
        {
            int r2 = lane >> 4, cc = lane & 15;
            const float* orow = wsK + r2*68;
            float acc = bo_r;
            #pragma unroll
            for (int dd4=0; dd4<16; ++dd4){
                float4 w4 = WO4[dd4*16 + cc];
                float4 o4 = *(const float4*)(orow + 4*dd4);  // broadcast per r-group
                acc += dot4(w4, o4);
            }
            int fc = 4*s + r2;
            float resid = x[xbase + fc*16 + cc] + hs[xbase + fc*16 + cc];
            S[OX2 + fc*16 + cc] = resid + acc;
        }
        wsync();
    }
    __syncthreads();

    // P6: MLP
    ln_stats16(S, tid);
    for (int i4 = tid; i4 < 384; i4 += 256){
        int f = i4 >> 2, c4 = i4 & 3;
        float4 v = X2f4[i4];
        float4 m4 = *(float4*)(S + OMEA + 4*c4);
        float4 r4 = *(float4*)(S + ORST + 4*c4);
        float gg = ln_m_g[f], b2 = ln_m_b[f];
        v.x = (v.x - m4.x)*r4.x*gg + b2;
        v.y = (v.y - m4.y)*r4.y*gg + b2;
        v.z = (v.z - m4.z)*r4.z*gg + b2;
        v.w = (v.w - m4.w)*r4.w*gg + b2;
        ((float4*)(S+OKL))[i4] = v;                   // ynorm in KL region
    }
    __syncthreads();
    for (int i4 = tid; i4 < 384; i4 += 256){
        int f = i4 >> 2, cb = i4 & 3;
        float4 acc = *(const float4*)(bm1 + 4*cb);
        #pragma unroll
        for (int c4=0;c4<4;++c4){
            float4 yn4 = ((float4*)(S+OKL))[f*4 + c4];
            float4 w0 = *(float4*)(S + OWM1 + (4*cb+0)*16 + 4*c4);
            float4 w1 = *(float4*)(S + OWM1 + (4*cb+1)*16 + 4*c4);
            float4 w2 = *(float4*)(S + OWM1 + (4*cb+2)*16 + 4*c4);
            float4 w3 = *(float4*)(S + OWM1 + (4*cb+3)*16 + 4*c4);
            acc.x += dot4(w0, yn4); acc.y += dot4(w1, yn4);
            acc.z += dot4(w2, yn4); acc.w += dot4(w3, yn4);
        }
        acc.x = gelu_erf(acc.x); acc.y = gelu_erf(acc.y);
        acc.z = gelu_erf(acc.z); acc.w = gelu_erf(acc.w);
        ((float4*)(S+OVL))[i4] = acc;                 // y1 in VL region
    }
    __syncthreads();
    for (int i4 = tid; i4 < 384; i4 += 256){
        int f = i4 >> 2, cb = i4 & 3;
        float4 acc = *(const float4*)(bm2 + 4*cb);
        #pragma unroll
        for (int c4=0;c4<4;++c4){
            float4 y14 = ((float4*)(S+OVL))[f*4 + c4];
            float4 w0 = *(float4*)(S + OWM2 + (4*cb+0)*16 + 4*c4);
            float4 w1 = *(float4*)(S + OWM2 + (4*cb+1)*16 + 4*c4);
            float4 w2 = *(float4*)(S + OWM2 + (4*cb+2)*16 + 4*c4);
            float4 w3 = *(float4*)(S + OWM2 + (4*cb+3)*16 + 4*c4);
            acc.x += dot4(w0, y14); acc.y += dot4(w1, y14);
            acc.z += dot4(w2, y14); acc.w += dot4(w3, y14);
        }
        float4 xv = X2f4[i4];
        X2f4[i4] = make_float4(xv.x+acc.x, xv.y+acc.y, xv.z+acc.z, xv.w+acc.w);
    }
    __syncthreads();

    // P7: conv_out + outer residual
    ln_stats16(S, tid);
    if (tid < 192){
        int ch = tid >= 96, f = tid - 96*ch;
        float gg = ln_o_g[f], b2 = ln_o_b[f];
        float acc = b_out[ch];
        #pragma unroll
        for (int c4=0;c4<4;++c4){
            float4 x4 = X2f4[f*4 + c4];
            float4 m4 = *(float4*)(S + OMEA + 4*c4);
            float4 r4 = *(float4*)(S + ORST + 4*c4);
            float4 w4 = *(const float4*)(w_out + ch*16 + 4*c4);
            float4 tm;
            tm.x = (x4.x - m4.x)*r4.x*gg + b2;
            tm.y = (x4.y - m4.y)*r4.y*gg + b2;
            tm.z = (x4.z - m4.z)*r4.z*gg + b2;
            tm.w = (x4.w - m4.w)*r4.w*gg + b2;
            acc += dot4(w4, tm);
        }
        size_t oidx = ((size_t)(b*2+ch)*T_ + t)*F_ + f;
        out[oidx] = input[oidx] + tanhf(acc);
    }
}

extern "C" void kernel_launch(void* const* d_in, const int* in_sizes, int n_in,
                              void* d_out, int out_size, void* d_ws, size_t ws_size,
                              hipStream_t stream)
{
    const float* input   = (const float*)d_in[0];
    const float* ln_in_g = (const float*)d_in[1];
    const float* ln_in_b = (const float*)d_in[2];
    const float* w_in    = (const float*)d_in[3];
    const float* b_in    = (const float*)d_in[4];
    const float* gru_wx  = (const float*)d_in[5];
    const float* gru_wh  = (const float*)d_in[6];
    const float* ln_att_g= (const float*)d_in[7];
    const float* ln_att_b= (const float*)d_in[8];
    const float* wq = (const float*)d_in[9];
    const float* bq = (const float*)d_in[10];
    const float* wk = (const float*)d_in[11];
    const float* bk = (const float*)d_in[12];
    const float* wv = (const float*)d_in[13];
    const float* bv = (const float*)d_in[14];
    const float* wo = (const float*)d_in[15];
    const float* bo = (const float*)d_in[16];
    const float* ln_m_g = (const float*)d_in[17];
    const float* ln_m_b = (const float*)d_in[18];
    const float* w_m1 = (const float*)d_in[19];
    const float* b_m1 = (const float*)d_in[20];
    const float* w_m2 = (const float*)d_in[21];
    const float* b_m2 = (const float*)d_in[22];
    const float* ln_out_g = (const float*)d_in[23];
    const float* ln_out_b = (const float*)d_in[24];
    const float* w_out = (const float*)d_in[25];
    const float* b_out = (const float*)d_in[26];
    float* out = (float*)d_out;

    float* x  = (float*)d_ws;                       // [B,T,F,C]
    float* hs = x + (size_t)B_*T_*F_*C_;            // [B,T,F,C]

    k_conv_in<<<B_*T_, 128, 0, stream>>>(input, ln_in_g, ln_in_b, w_in, b_in, x);
    k_gru<<<768, 64, 0, stream>>>(x, gru_wx, gru_wh, hs, out);
    k_tail<<<B_*T_, 256, 0, stream>>>(x, hs, input, ln_att_g, ln_att_b,
        wq, bq, wk, bk, wv, bv, wo, bo, ln_m_g, ln_m_b, w_m1, b_m1, w_m2, b_m2,
        ln_out_g, ln_out_b, w_out, b_out, out);
}